// Round 1
// baseline (571.417 us; speedup 1.0000x reference)
//
#include <hip/hip_runtime.h>
#include <math.h>

#define N_  32
#define C_  64
#define HW  192          // h == w == 192
#define NC  (N_ * C_)    // 2048 (n,c) tiles

__device__ __forceinline__ float wave_max(float v) {
#pragma unroll
    for (int off = 32; off; off >>= 1) v = fmaxf(v, __shfl_xor(v, off));
    return v;
}
__device__ __forceinline__ float wave_sum(float v) {
#pragma unroll
    for (int off = 32; off; off >>= 1) v += __shfl_xor(v, off);
    return v;
}

// 256-thread block reductions (4 waves), red[] is shared float[4]
__device__ __forceinline__ float block_max(float v, float* red) {
    const int w = threadIdx.x >> 6, lane = threadIdx.x & 63;
    v = wave_max(v);
    if (lane == 0) red[w] = v;
    __syncthreads();
    float r = fmaxf(fmaxf(red[0], red[1]), fmaxf(red[2], red[3]));
    __syncthreads();
    return r;
}
__device__ __forceinline__ float block_sum(float v, float* red) {
    const int w = threadIdx.x >> 6, lane = threadIdx.x & 63;
    v = wave_sum(v);
    if (lane == 0) red[w] = v;
    __syncthreads();
    float r = (red[0] + red[1]) + (red[2] + red[3]);
    __syncthreads();
    return r;
}

__global__ void k_zero(float* __restrict__ S, int n) {
    int i = blockIdx.x * blockDim.x + threadIdx.x;
    if (i < n) S[i] = 0.0f;
}

// One block per (n,c) tile. Reads the 192x192 f32 tile of both tensors once.
// Produces: simpos[b] and atomic channel-sum accumulation into S[n][4][192].
__global__ __launch_bounds__(256) void k_stage1(const float* __restrict__ outp,
                                                const float* __restrict__ tgtp,
                                                float* __restrict__ simpos,
                                                float* __restrict__ S) {
    __shared__ float rowmax[HW];
    __shared__ float colpart[4][HW];
    __shared__ float colmax[HW];
    __shared__ float A[4][HW];   // 0:Ao_h 1:Ao_w 2:At_h 3:At_w
    __shared__ float red[4];

    const int b    = blockIdx.x;
    const int n    = b >> 6;
    const int tid  = threadIdx.x;
    const int w    = tid >> 6;
    const int lane = tid & 63;
    const float NEG = -INFINITY;

    for (int t = 0; t < 2; ++t) {
        const float* X = (t == 0 ? outp : tgtp) + (size_t)b * (HW * HW);

        // --- row/col maxes. Wave w owns rows r = w, w+4, ...; lanes 0..47
        // each load one float4 (768B contiguous per row per wave). ---
        float4 colp = make_float4(NEG, NEG, NEG, NEG);
        for (int r = w; r < HW; r += 4) {
            float rm = NEG;
            if (lane < 48) {
                const float4 v = ((const float4*)(X + r * HW))[lane];
                colp.x = fmaxf(colp.x, v.x);
                colp.y = fmaxf(colp.y, v.y);
                colp.z = fmaxf(colp.z, v.z);
                colp.w = fmaxf(colp.w, v.w);
                rm = fmaxf(fmaxf(v.x, v.y), fmaxf(v.z, v.w));
            }
            rm = wave_max(rm);
            if (lane == 0) rowmax[r] = rm;
        }
        if (lane < 48) {
            colpart[w][4 * lane + 0] = colp.x;
            colpart[w][4 * lane + 1] = colp.y;
            colpart[w][4 * lane + 2] = colp.z;
            colpart[w][4 * lane + 3] = colp.w;
        }
        __syncthreads();
        if (tid < HW) {
            colmax[tid] = fmaxf(fmaxf(colpart[0][tid], colpart[1][tid]),
                                fmaxf(colpart[2][tid], colpart[3][tid]));
        }
        __syncthreads();

        // --- softmax + l2norm fused: a_i = exp(x_i - M) / ||exp(x - M)||.
        // (softmax denominator cancels in the cosine normalization;
        //  eps clamp inert since ||p|| >= 1/sqrt(192) >> 1e-8) ---
        for (int vsel = 0; vsel < 2; ++vsel) {
            const float* src = (vsel == 0) ? rowmax : colmax;  // h-vec, w-vec
            float x = (tid < HW) ? src[tid] : NEG;
            float M = block_max(x, red);
            float e = (tid < HW) ? expf(x - M) : 0.0f;
            float ss = block_sum(e * e, red);
            if (tid < HW) A[t * 2 + vsel][tid] = e / sqrtf(ss);
        }
        __syncthreads();
    }

    // --- sim_pos[b] = 0.5*(dot(Ao_h,At_h) + dot(Ao_w,At_w)) ---
    float p = 0.0f;
    if (tid < HW) p = A[0][tid] * A[2][tid] + A[1][tid] * A[3][tid];
    float sp = block_sum(p, red);
    if (tid == 0) simpos[b] = 0.5f * sp;

    // --- channel sums: S[n][v][k], v: 0=sum_c Ao_h, 1=sum_c At_h,
    //                                 2=sum_c Ao_w, 3=sum_c At_w ---
    if (tid < HW) {
        float* Sn = S + (size_t)n * 4 * HW;
        atomicAdd(Sn + 0 * HW + tid, A[0][tid]);
        atomicAdd(Sn + 1 * HW + tid, A[2][tid]);
        atomicAdd(Sn + 2 * HW + tid, A[1][tid]);
        atomicAdd(Sn + 3 * HW + tid, A[3][tid]);
    }
}

// One block per n: sim[n] = 0.5*(dot(S_oh,S_th) + dot(S_ow,S_tw));
// loss[n,c] = -log(simpos/sim) / (N*C)
__global__ __launch_bounds__(256) void k_stage2(const float* __restrict__ simpos,
                                                const float* __restrict__ S,
                                                float* __restrict__ loss) {
    __shared__ float red[4];
    const int n = blockIdx.x, tid = threadIdx.x;
    const float* Sn = S + (size_t)n * 4 * HW;
    float p = 0.0f;
    if (tid < HW)
        p = Sn[tid] * Sn[HW + tid] + Sn[2 * HW + tid] * Sn[3 * HW + tid];
    float sim = 0.5f * block_sum(p, red);
    if (tid < C_) {
        loss[n * C_ + tid] =
            -logf(simpos[n * C_ + tid] / sim) * (1.0f / (N_ * C_));
    }
}

extern "C" void kernel_launch(void* const* d_in, const int* in_sizes, int n_in,
                              void* d_out, int out_size, void* d_ws, size_t ws_size,
                              hipStream_t stream) {
    const float* outp = (const float*)d_in[0];
    const float* tgtp = (const float*)d_in[1];
    float* simpos = (float*)d_ws;          // NC floats
    float* S      = simpos + NC;           // N_*4*HW floats (accumulators)
    float* lossp  = (float*)d_out;         // NC floats

    const int s_elems = N_ * 4 * HW;       // 24576
    hipLaunchKernelGGL(k_zero, dim3((s_elems + 255) / 256), dim3(256), 0, stream,
                       S, s_elems);
    hipLaunchKernelGGL(k_stage1, dim3(NC), dim3(256), 0, stream,
                       outp, tgtp, simpos, S);
    hipLaunchKernelGGL(k_stage2, dim3(N_), dim3(256), 0, stream,
                       simpos, S, lossp);
}